// Round 8
// baseline (211.729 us; speedup 1.0000x reference)
//
#include <hip/hip_runtime.h>
#include <hip/hip_bf16.h>

#define N 8192
#define D 1024
#define MARGIN 1.0f
#define EPS 1e-6f
#define TSTR 132   // LDS tile stride in u16 (264 B = 66 dw == 2 mod 32 -> 2-way, free)

typedef __attribute__((ext_vector_type(8))) short bf16x8;
typedef __attribute__((ext_vector_type(4))) float f32x4;
typedef __attribute__((ext_vector_type(8))) _Float16 f16x8;
typedef __attribute__((ext_vector_type(4))) _Float16 f16x4;
typedef __attribute__((ext_vector_type(8))) unsigned short u16x8;
typedef __attribute__((ext_vector_type(4))) unsigned short u16x4;

__device__ inline unsigned short f2bf(float x) {
    unsigned u = __float_as_uint(x);
    unsigned r = (u + 0x7FFFu + ((u >> 16) & 1u)) >> 16;  // RNE
    return (unsigned short)r;
}

__device__ inline float h2f(unsigned hb) {
    return (float)__builtin_bit_cast(_Float16, (unsigned short)hb);
}

// decode linear id -> (a, b) with b >= a over 64x64 upper-tri tile grid
__device__ inline void tri_decode(int l, int& a, int& b) {
    int bb = (int)((sqrtf(8.0f * (float)l + 1.0f) - 1.0f) * 0.5f);
    while ((bb + 1) * (bb + 2) / 2 <= l) ++bb;
    while (bb * (bb + 1) / 2 > l) --bb;
    b = bb;
    a = l - bb * (bb + 1) / 2;
}

// Kernel 0: fp32 -> bf16 copy + per-row sum of squares + (first 32 blocks) cls bytes.
__global__ __launch_bounds__(256) void prep_kernel(const float* __restrict__ E,
                                                   const int* __restrict__ target,
                                                   unsigned short* __restrict__ Ebf,
                                                   float* __restrict__ sq,
                                                   unsigned char* __restrict__ cls) {
    const int r = blockIdx.x;
    const int tid = threadIdx.x;
    if (r < 32) {
        const int idx = r * 256 + tid;
        cls[idx] = (unsigned char)target[idx];
    }
    const float4 v = ((const float4*)(E + (size_t)r * D))[tid];
    ushort4 o;
    o.x = f2bf(v.x); o.y = f2bf(v.y); o.z = f2bf(v.z); o.w = f2bf(v.w);
    ((ushort4*)(Ebf + (size_t)r * D))[tid] = o;
    float s = v.x * v.x + v.y * v.y + v.z * v.z + v.w * v.w;
    for (int off = 32; off > 0; off >>= 1) s += __shfl_down(s, off);
    __shared__ float red[4];
    const int lane = tid & 63, wave = tid >> 6;
    if (lane == 0) red[wave] = s;
    __syncthreads();
    if (tid == 0) sq[r] = red[0] + red[1] + red[2] + red[3];
}

// Kernel 1: symmetric D2, upper-triangle-only storage.
// Computes lower-tri tile (rows rm=by*128 >= cols cn=bx*128), stores ONLY its
// transpose (rows cn.., cols rm..) via the coalesced Ts path — including diag
// (bit-identical by MFMA determinism with identical A/B operands).
__global__ __launch_bounds__(256) void gemm_kernel(const unsigned short* __restrict__ E,
                                                   const float* __restrict__ sq,
                                                   _Float16* __restrict__ D2h) {
    __shared__ char smem[128 * TSTR * 2];                 // 33792 B
    unsigned short* As = (unsigned short*)smem;           // 8 KB (K-loop)
    unsigned short* Bs = (unsigned short*)(smem + 8192);  // 8 KB (K-loop)
    _Float16* Ts = (_Float16*)smem;                       // 128 x (stride 132) fp16 (epilogue)

    const int tid = threadIdx.x;
    const int lane = tid & 63;
    const int wave = tid >> 6;
    const int wm = wave & 1, wn = wave >> 1;

    int bx, by;
    tri_decode(blockIdx.x, bx, by);
    const int rm = by * 128;
    const int cn = bx * 128;

    const int srow = tid >> 2;
    const int scol = (tid & 3) * 8;

    const unsigned short* gA = E + (size_t)(rm + srow) * D + scol;
    const unsigned short* gB = E + (size_t)(cn + srow) * D + scol;

    f32x4 acc[4][4] = {};

    const int kq = (lane >> 4) * 8;
    const int mr = lane & 15;

    for (int k0 = 0; k0 < D; k0 += 32) {
        __builtin_amdgcn_global_load_lds(
            (const __attribute__((address_space(1))) unsigned int*)(gA + k0),
            (__attribute__((address_space(3))) unsigned int*)((char*)As + wave * 1024), 16, 0, 0);
        __builtin_amdgcn_global_load_lds(
            (const __attribute__((address_space(1))) unsigned int*)(gA + (size_t)64 * D + k0),
            (__attribute__((address_space(3))) unsigned int*)((char*)As + 4096 + wave * 1024), 16, 0, 0);
        __builtin_amdgcn_global_load_lds(
            (const __attribute__((address_space(1))) unsigned int*)(gB + k0),
            (__attribute__((address_space(3))) unsigned int*)((char*)Bs + wave * 1024), 16, 0, 0);
        __builtin_amdgcn_global_load_lds(
            (const __attribute__((address_space(1))) unsigned int*)(gB + (size_t)64 * D + k0),
            (__attribute__((address_space(3))) unsigned int*)((char*)Bs + 4096 + wave * 1024), 16, 0, 0);
        __syncthreads();

        bf16x8 af[4], bfr[4];
#pragma unroll
        for (int mi = 0; mi < 4; ++mi)
            af[mi] = *(const bf16x8*)(As + (wm * 64 + mi * 16 + mr) * 32 + kq);
#pragma unroll
        for (int ni = 0; ni < 4; ++ni)
            bfr[ni] = *(const bf16x8*)(Bs + (wn * 64 + ni * 16 + mr) * 32 + kq);
#pragma unroll
        for (int mi = 0; mi < 4; ++mi)
#pragma unroll
            for (int ni = 0; ni < 4; ++ni)
                acc[mi][ni] = __builtin_amdgcn_mfma_f32_16x16x32_bf16(af[mi], bfr[ni], acc[mi][ni], 0, 0, 0);
        __syncthreads();
    }

    const int crow = (lane >> 4) * 4;
    const int ccol = lane & 15;
    float sqj[4];
#pragma unroll
    for (int ni = 0; ni < 4; ++ni)
        sqj[ni] = sq[cn + wn * 64 + ni * 16 + ccol];
#pragma unroll
    for (int mi = 0; mi < 4; ++mi) {
        const int lrow = wm * 64 + mi * 16 + crow;
        const int i0 = rm + lrow;
        float sqi[4];
#pragma unroll
        for (int r = 0; r < 4; ++r) sqi[r] = sq[i0 + r];
#pragma unroll
        for (int ni = 0; ni < 4; ++ni) {
            const int lcol = wn * 64 + ni * 16 + ccol;
            f16x4 tv;
#pragma unroll
            for (int r = 0; r < 4; ++r) {
                float d2 = fmaxf(sqi[r] + sqj[ni] - 2.0f * acc[mi][ni][r], 0.0f);
                tv[r] = (_Float16)d2;
            }
            *(f16x4*)(Ts + (size_t)lcol * TSTR + lrow) = tv;  // transposed stage
        }
    }
    __syncthreads();
    // coalesced store of the transposed tile: row rt (global row cn+rt), cols rm..rm+127
#pragma unroll
    for (int it = 0; it < 8; ++it) {
        const int rt = it * 16 + (tid >> 4);
        const int seg = tid & 15;
        f16x4 v0 = *(const f16x4*)(Ts + (size_t)rt * TSTR + seg * 8);
        f16x4 v1 = *(const f16x4*)(Ts + (size_t)rt * TSTR + seg * 8 + 4);
        f16x8 v = __builtin_shufflevector(v0, v1, 0, 1, 2, 3, 4, 5, 6, 7);
        *(f16x8*)(D2h + (size_t)(cn + rt) * N + rm + seg * 8) = v;
    }
}

// Kernel 2: tile mineA — per-tile row/col hardest-pos (u16 max) / hardest-neg (u16 min).
// Tile (a,b), b>=a: rows a*128.. (anchors A), cols b*128.. (anchors B).
// Row partials -> Ppart/Npart[slot b][anchor in A]; col partials -> [slot a][anchor in B].
// Diagonal: row partials only (col would collide; symmetric tile covers it).
__global__ __launch_bounds__(256) void mineA_kernel(const _Float16* __restrict__ D2h,
                                                    const unsigned char* __restrict__ cls,
                                                    unsigned short* __restrict__ Ppart,
                                                    unsigned short* __restrict__ Npart) {
    __shared__ unsigned short tile[128 * TSTR];  // 33792 B
    __shared__ unsigned char clsA[128], clsB[128];
    __shared__ unsigned rpm[256], rnm[256];
    const int tid = threadIdx.x;
    int a, b;
    tri_decode(blockIdx.x, a, b);

    if (tid < 128) clsA[tid] = cls[a * 128 + tid];
    else           clsB[tid - 128] = cls[b * 128 + (tid - 128)];

    const unsigned short* g = (const unsigned short*)D2h + (size_t)(a * 128) * N + b * 128;
#pragma unroll
    for (int it = 0; it < 8; ++it) {
        const int q = it * 256 + tid;
        const int r = q >> 4, seg = q & 15;
        u16x8 v = *(const u16x8*)(g + (size_t)r * N + seg * 8);
        *(u16x4*)(tile + r * TSTR + seg * 8)     = __builtin_shufflevector(v, v, 0, 1, 2, 3);
        *(u16x4*)(tile + r * TSTR + seg * 8 + 4) = __builtin_shufflevector(v, v, 4, 5, 6, 7);
    }
    __syncthreads();

    // Row partials: 2 threads per row (halves of 64 cols).
    {
        const int r = tid >> 1, half = tid & 1;
        const unsigned rc = clsA[r];
        const unsigned short* rowp = tile + r * TSTR + half * 64;
        const unsigned char* cb = clsB + half * 64;
        unsigned pm = 0u, nm = 0xFFFFu;
#pragma unroll
        for (int k = 0; k < 16; ++k) {
            u16x4 v = *(const u16x4*)(rowp + k * 4);
            unsigned c4 = *(const unsigned*)(cb + k * 4);
#pragma unroll
            for (int e = 0; e < 4; ++e) {
                const unsigned hb = v[e];
                const bool s = ((c4 >> (8 * e)) & 0xFFu) == rc;
                pm = max(pm, s ? hb : 0u);
                nm = min(nm, s ? 0xFFFFu : hb);
            }
        }
        rpm[tid] = pm; rnm[tid] = nm;
    }
    __syncthreads();
    if (tid < 128) {
        const unsigned pm = max(rpm[2 * tid], rpm[2 * tid + 1]);
        const unsigned nm = min(rnm[2 * tid], rnm[2 * tid + 1]);
        Ppart[(size_t)b * N + a * 128 + tid] = (unsigned short)pm;
        Npart[(size_t)b * N + a * 128 + tid] = (unsigned short)nm;
    }

    if (a != b) {
        __syncthreads();
        // Col partials: 2 threads per col (halves of 64 rows); lane-coalesced u16 reads.
        const int c = tid & 127, rh = tid >> 7;
        const unsigned cc = clsB[c];
        unsigned pm = 0u, nm = 0xFFFFu;
#pragma unroll 8
        for (int k = 0; k < 64; ++k) {
            const int rr = rh * 64 + k;
            const unsigned hb = tile[rr * TSTR + c];
            const bool s = (clsA[rr] == cc);
            pm = max(pm, s ? hb : 0u);
            nm = min(nm, s ? 0xFFFFu : hb);
        }
        rpm[tid] = pm; rnm[tid] = nm;
        __syncthreads();
        if (tid < 128) {
            const unsigned pmc = max(rpm[tid], rpm[tid + 128]);
            const unsigned nmc = min(rnm[tid], rnm[tid + 128]);
            Ppart[(size_t)a * N + b * 128 + tid] = (unsigned short)pmc;
            Npart[(size_t)a * N + b * 128 + tid] = (unsigned short)nmc;
        }
    }
}

// Kernel 3: foldA — per anchor: lob = max slot pmax; nmb = min slot nmin.
__global__ __launch_bounds__(256) void foldA_kernel(const unsigned short* __restrict__ Ppart,
                                                    const unsigned short* __restrict__ Npart,
                                                    unsigned short* __restrict__ lob,
                                                    unsigned short* __restrict__ nmb) {
    const int i = blockIdx.x * 256 + threadIdx.x;
    unsigned pm = 0u, nm = 0xFFFFu;
#pragma unroll 8
    for (int s = 0; s < 64; ++s) {
        pm = max(pm, (unsigned)Ppart[(size_t)s * N + i]);
        nm = min(nm, (unsigned)Npart[(size_t)s * N + i]);
    }
    lob[i] = (unsigned short)pm;
    nmb[i] = (unsigned short)nm;
}

// Kernel 4: tile mineB — per-tile min{d2 bits > lob(anchor)} (strict > excludes
// all positives and self; no class data needed). Same slot scheme as mineA.
__global__ __launch_bounds__(256) void mineB_kernel(const _Float16* __restrict__ D2h,
                                                    const unsigned short* __restrict__ lob,
                                                    unsigned short* __restrict__ Spart) {
    __shared__ unsigned short tile[128 * TSTR];
    __shared__ unsigned short lobA[128], lobB[128];
    __shared__ unsigned rsm[256];
    const int tid = threadIdx.x;
    int a, b;
    tri_decode(blockIdx.x, a, b);

    if (tid < 128) lobA[tid] = lob[a * 128 + tid];
    else           lobB[tid - 128] = lob[b * 128 + (tid - 128)];

    const unsigned short* g = (const unsigned short*)D2h + (size_t)(a * 128) * N + b * 128;
#pragma unroll
    for (int it = 0; it < 8; ++it) {
        const int q = it * 256 + tid;
        const int r = q >> 4, seg = q & 15;
        u16x8 v = *(const u16x8*)(g + (size_t)r * N + seg * 8);
        *(u16x4*)(tile + r * TSTR + seg * 8)     = __builtin_shufflevector(v, v, 0, 1, 2, 3);
        *(u16x4*)(tile + r * TSTR + seg * 8 + 4) = __builtin_shufflevector(v, v, 4, 5, 6, 7);
    }
    __syncthreads();

    {
        const int r = tid >> 1, half = tid & 1;
        const unsigned lr = lobA[r];
        const unsigned short* rowp = tile + r * TSTR + half * 64;
        unsigned sm = 0xFFFFu;
#pragma unroll
        for (int k = 0; k < 16; ++k) {
            u16x4 v = *(const u16x4*)(rowp + k * 4);
#pragma unroll
            for (int e = 0; e < 4; ++e) {
                const unsigned hb = v[e];
                sm = min(sm, hb > lr ? hb : 0xFFFFu);
            }
        }
        rsm[tid] = sm;
    }
    __syncthreads();
    if (tid < 128)
        Spart[(size_t)b * N + a * 128 + tid] =
            (unsigned short)min(rsm[2 * tid], rsm[2 * tid + 1]);

    if (a != b) {
        __syncthreads();
        const int c = tid & 127, rh = tid >> 7;
        const unsigned lc = lobB[c];
        unsigned sm = 0xFFFFu;
#pragma unroll 8
        for (int k = 0; k < 64; ++k) {
            const unsigned hb = tile[(rh * 64 + k) * TSTR + c];
            sm = min(sm, hb > lc ? hb : 0xFFFFu);
        }
        rsm[tid] = sm;
        __syncthreads();
        if (tid < 128)
            Spart[(size_t)a * N + b * 128 + tid] =
                (unsigned short)min(rsm[tid], rsm[tid + 128]);
    }
}

// Kernel 5: foldB — per anchor: sm = min slot; loss from values (index-free).
__global__ __launch_bounds__(256) void foldB_kernel(const unsigned short* __restrict__ Spart,
                                                    const unsigned short* __restrict__ lob,
                                                    const unsigned short* __restrict__ nmb,
                                                    float* __restrict__ loss_arr) {
    const int i = blockIdx.x * 256 + threadIdx.x;
    unsigned sm = 0xFFFFu;
#pragma unroll 8
    for (int s = 0; s < 64; ++s)
        sm = min(sm, (unsigned)Spart[(size_t)s * N + i]);
    const float lo = h2f(lob[i]);
    const float dp = sqrtf(lo);
    const float hw = dp + MARGIN;
    const float hi = hw * hw;
    const float smv = h2f(sm);                    // 0xFFFF -> NaN -> fallback
    const float dn2 = (smv < hi) ? smv : h2f(nmb[i]);
    loss_arr[i] = fmaxf(dp - sqrtf(dn2) + MARGIN, 0.0f);
}

// Kernel 6: mean over 8192 per-anchor losses.
__global__ __launch_bounds__(256) void reduce_kernel(const float* __restrict__ loss_arr,
                                                     float* __restrict__ out) {
    const int tid = threadIdx.x;
    float s = 0.0f;
    for (int k = tid; k < N; k += 256) s += loss_arr[k];
    for (int off = 32; off > 0; off >>= 1) s += __shfl_down(s, off);
    __shared__ float red[4];
    const int lane = tid & 63, wave = tid >> 6;
    if (lane == 0) red[wave] = s;
    __syncthreads();
    if (tid == 0) out[0] = (red[0] + red[1] + red[2] + red[3]) * (1.0f / N);
}

extern "C" void kernel_launch(void* const* d_in, const int* in_sizes, int n_in,
                              void* d_out, int out_size, void* d_ws, size_t ws_size,
                              hipStream_t stream) {
    const float* E = (const float*)d_in[0];
    const int* target = (const int*)d_in[1];
    float* out = (float*)d_out;
    char* ws = (char*)d_ws;

    // Workspace layout (~147.2 MB):
    unsigned short* Ebf   = (unsigned short*)ws;                          // 16 MB
    float* sq             = (float*)(ws + (size_t)16777216);              // 32 KB
    float* loss_arr       = (float*)(ws + (size_t)16809984);              // 32 KB
    unsigned char* cls    = (unsigned char*)(ws + (size_t)16842752);      // 8 KB (pad 32K)
    unsigned short* lob   = (unsigned short*)(ws + (size_t)16875520);     // 16 KB (pad 32K)
    unsigned short* nmb   = (unsigned short*)(ws + (size_t)16908288);     // 16 KB (pad 32K)
    unsigned short* Ppart = (unsigned short*)(ws + (size_t)16941056);     // 1 MB
    unsigned short* Npart = (unsigned short*)(ws + (size_t)17989632);     // 1 MB
    unsigned short* Spart = (unsigned short*)(ws + (size_t)19038208);     // 1 MB
    _Float16* D2h         = (_Float16*)(ws + (size_t)20086784);           // 128 MB

    prep_kernel<<<N, 256, 0, stream>>>(E, target, Ebf, sq, cls);
    gemm_kernel<<<2080, 256, 0, stream>>>(Ebf, sq, D2h);       // upper-tri tiles
    mineA_kernel<<<2080, 256, 0, stream>>>(D2h, cls, Ppart, Npart);
    foldA_kernel<<<N / 256, 256, 0, stream>>>(Ppart, Npart, lob, nmb);
    mineB_kernel<<<2080, 256, 0, stream>>>(D2h, lob, Spart);
    foldB_kernel<<<N / 256, 256, 0, stream>>>(Spart, lob, nmb, loss_arr);
    reduce_kernel<<<1, 256, 0, stream>>>(loss_arr, out);
}